// Round 5
// baseline (49.733 us; speedup 1.0000x reference)
//
#include <hip/hip_runtime.h>
#include <hip/hip_bf16.h>

// out[b,i,j,o] = (x[b,min]·M_lo[o] + s_lo[o]) + (x[b,max]·M_hi[o] + s_hi[o])
// where M_lo[o] = W1^T Wc[o,:100], M_hi[o] = W1^T Wc[o,100:],
//       s_lo[o] = b1·Wc[o,:100] + bc[o], s_hi[o] = b1·Wc[o,100:].

#define NA 13
#define DM 512
#define NOH 8   // 4 outputs x {lo,hi}

typedef float fv4 __attribute__((ext_vector_type(4)));

__global__ __launch_bounds__(512) void precompute_M(
    const float* __restrict__ W1, const float* __restrict__ b1,
    const float* __restrict__ Wc, const float* __restrict__ bc,
    float* __restrict__ M, float* __restrict__ s) {
    int oh = blockIdx.x;          // 0..7: oh = half*4 + o
    int o = oh & 3, half = oh >> 2;
    int d = threadIdx.x;          // 0..511
    const float* wc = Wc + o * 200 + half * 100;
    // 4 independent chains: break the serial FMA dependency
    float a0 = 0.f, a1 = 0.f, a2 = 0.f, a3 = 0.f;
#pragma unroll
    for (int c = 0; c < 100; c += 4) {
        a0 = fmaf(wc[c + 0], W1[(c + 0) * DM + d], a0);
        a1 = fmaf(wc[c + 1], W1[(c + 1) * DM + d], a1);
        a2 = fmaf(wc[c + 2], W1[(c + 2) * DM + d], a2);
        a3 = fmaf(wc[c + 3], W1[(c + 3) * DM + d], a3);
    }
    M[oh * DM + d] = (a0 + a1) + (a2 + a3);
    if (d == 0) {
        float s0 = (half == 0) ? bc[o] : 0.f, s1 = 0.f, s2 = 0.f, s3 = 0.f;
#pragma unroll
        for (int c = 0; c < 100; c += 4) {
            s0 = fmaf(wc[c + 0], b1[c + 0], s0);
            s1 = fmaf(wc[c + 1], b1[c + 1], s1);
            s2 = fmaf(wc[c + 2], b1[c + 2], s2);
            s3 = fmaf(wc[c + 3], b1[c + 3], s3);
        }
        s[oh] = (s0 + s1) + (s2 + s3);
    }
}

__global__ __launch_bounds__(256) void edge_main(
    const float* __restrict__ x, const float* __restrict__ M,
    const float* __restrict__ s, float* __restrict__ out, int B2) {
    const int lane = threadIdx.x & 63;
    const int wave = threadIdx.x >> 6;
    const int b0 = blockIdx.x;
    const int b1 = blockIdx.x + B2;

    const float* xb0 = x + (size_t)b0 * (NA * DM);
    const float* xb1 = x + (size_t)b1 * (NA * DM);

    // Issue ALL x loads for both batches first: up to 16 x 16B in flight
    // per wave. `a < NA` is wave-uniform.
    fv4 xA0[4], xB0[4], xA1[4], xB1[4];
#pragma unroll
    for (int k = 0; k < 4; ++k) {
        const int a = wave + 4 * k;
        if (a < NA) {
            xA0[k] = *(const fv4*)(xb0 + a * DM + lane * 4);
            xB0[k] = *(const fv4*)(xb0 + a * DM + 256 + lane * 4);
            xA1[k] = *(const fv4*)(xb1 + a * DM + lane * 4);
            xB1[k] = *(const fv4*)(xb1 + a * DM + 256 + lane * 4);
        }
    }

    // Per-lane M slices: lane covers d = lane*4..+3 and d = 256+lane*4..+3
    fv4 mA[NOH], mB[NOH];
#pragma unroll
    for (int oh = 0; oh < NOH; ++oh) {
        mA[oh] = *(const fv4*)(M + oh * DM + lane * 4);
        mB[oh] = *(const fv4*)(M + oh * DM + 256 + lane * 4);
    }
    const float s_lane = s[lane & 7];

    const bool m1 = (lane & 1) != 0;
    const bool m2 = (lane & 2) != 0;
    const bool m4 = (lane & 4) != 0;

    __shared__ float G[2][NA][NOH];

#pragma unroll
    for (int which = 0; which < 2; ++which) {
#pragma unroll
        for (int k = 0; k < 4; ++k) {
            const int a = wave + 4 * k;
            if (a < NA) {
                const fv4 xA = which ? xA1[k] : xA0[k];
                const fv4 xB = which ? xB1[k] : xB0[k];
                float acc[NOH];
#pragma unroll
                for (int oh = 0; oh < NOH; ++oh) {
                    float v = xA.x * mA[oh].x;
                    v = fmaf(xA.y, mA[oh].y, v);
                    v = fmaf(xA.z, mA[oh].z, v);
                    v = fmaf(xA.w, mA[oh].w, v);
                    v = fmaf(xB.x, mB[oh].x, v);
                    v = fmaf(xB.y, mB[oh].y, v);
                    v = fmaf(xB.z, mB[oh].z, v);
                    v = fmaf(xB.w, mB[oh].w, v);
                    acc[oh] = v;
                }
                // transpose-reduce: 3 merge steps leave lane l holding
                // oh=(l&7)'s 8-lane partial; 3 butterflies finish 64 lanes.
                float r1[4];
#pragma unroll
                for (int q = 0; q < 4; ++q) {
                    float keep = m1 ? acc[2 * q + 1] : acc[2 * q];
                    float send = m1 ? acc[2 * q]     : acc[2 * q + 1];
                    r1[q] = keep + __shfl_xor(send, 1, 64);
                }
                float r2[2];
#pragma unroll
                for (int q = 0; q < 2; ++q) {
                    float keep = m2 ? r1[2 * q + 1] : r1[2 * q];
                    float send = m2 ? r1[2 * q]     : r1[2 * q + 1];
                    r2[q] = keep + __shfl_xor(send, 2, 64);
                }
                float keep = m4 ? r2[1] : r2[0];
                float send = m4 ? r2[0] : r2[1];
                float t = keep + __shfl_xor(send, 4, 64);
                t += __shfl_xor(t, 8, 64);
                t += __shfl_xor(t, 16, 64);
                t += __shfl_xor(t, 32, 64);
                if (lane < NOH) G[which][a][lane] = t + s_lane;
            }
        }
    }
    __syncthreads();

    // 2 x 169 pairs, one float4 (4 outputs) per store, coalesced
    for (int e = threadIdx.x; e < 2 * NA * NA; e += 256) {
        const int which = (e >= NA * NA) ? 1 : 0;
        const int t = e - which * NA * NA;
        const int b = which ? b1 : b0;
        int i = t / NA, j = t % NA;
        int lo = i < j ? i : j;
        int hi = i < j ? j : i;
        fv4 v;
        v.x = G[which][lo][0] + G[which][hi][4];
        v.y = G[which][lo][1] + G[which][hi][5];
        v.z = G[which][lo][2] + G[which][hi][6];
        v.w = G[which][lo][3] + G[which][hi][7];
        ((fv4*)(out + (size_t)b * (NA * NA * 4)))[t] = v;
    }
}

extern "C" void kernel_launch(void* const* d_in, const int* in_sizes, int n_in,
                              void* d_out, int out_size, void* d_ws, size_t ws_size,
                              hipStream_t stream) {
    const float* x  = (const float*)d_in[0];
    const float* W1 = (const float*)d_in[1];
    const float* b1 = (const float*)d_in[2];
    const float* Wc = (const float*)d_in[3];
    const float* bc = (const float*)d_in[4];
    float* out = (float*)d_out;
    const int B = in_sizes[0] / (NA * DM);   // 8192
    const int B2 = B / 2;                    // 4096

    float* M = (float*)d_ws;            // 8*512 floats = 16 KB
    float* s = M + NOH * DM;            // 8 floats

    precompute_M<<<8, 512, 0, stream>>>(W1, b1, Wc, bc, M, s);
    edge_main<<<B2, 256, 0, stream>>>(x, M, s, out, B2);
}

// Round 6
// 46.385 us; speedup vs baseline: 1.0722x; 1.0722x over previous
//
#include <hip/hip_runtime.h>
#include <hip/hip_bf16.h>

// out[b,i,j,o] = (x[b,min]·M_lo[o] + s_lo[o]) + (x[b,max]·M_hi[o] + s_hi[o])
// where M_lo[o] = W1^T Wc[o,:100], M_hi[o] = W1^T Wc[o,100:],
//       s_lo[o] = b1·Wc[o,:100] + bc[o], s_hi[o] = b1·Wc[o,100:].

#define NA 13
#define DM 512
#define NOH 8   // 4 outputs x {lo,hi}
#define LEN 100

typedef float fv4 __attribute__((ext_vector_type(4)));

// 8 blocks x 512 threads. Block b owns d in [b*64, b*64+64). Stage the
// W1 slice (100 x 64 floats = 25.6 KB) in LDS via pipelined float4 loads,
// then thread (oh = tid>>6, d = tid&63) accumulates 100 FMAs from LDS with
// wave-uniform wc[c] scalar reads. Removes the ~5us latency-bound serial
// prefix of the old version (100 global loads, 4 in flight).
__global__ __launch_bounds__(512) void precompute_M(
    const float* __restrict__ W1, const float* __restrict__ b1,
    const float* __restrict__ Wc, const float* __restrict__ bc,
    float* __restrict__ M, float* __restrict__ s) {
    __shared__ float W1s[LEN * 64];
    const int tid = threadIdx.x;
    const int d_base = blockIdx.x * 64;

    // cooperative staged load: 100 rows x 16 float4 = 1600 chunks
#pragma unroll
    for (int r = 0; r < 4; ++r) {
        int idx = tid + r * 512;
        if (idx < LEN * 16) {
            int c = idx >> 4, d4 = idx & 15;
            *(fv4*)(W1s + c * 64 + d4 * 4) =
                *(const fv4*)(W1 + c * DM + d_base + d4 * 4);
        }
    }
    __syncthreads();

    const int oh = tid >> 6;      // wave-uniform: 0..7
    const int d = tid & 63;
    const int o = oh & 3, half = oh >> 2;
    const float* wc = Wc + o * 200 + half * 100;   // wave-uniform pointer

    float a0 = 0.f, a1 = 0.f, a2 = 0.f, a3 = 0.f;
#pragma unroll
    for (int c = 0; c < LEN; c += 4) {
        a0 = fmaf(wc[c + 0], W1s[(c + 0) * 64 + d], a0);
        a1 = fmaf(wc[c + 1], W1s[(c + 1) * 64 + d], a1);
        a2 = fmaf(wc[c + 2], W1s[(c + 2) * 64 + d], a2);
        a3 = fmaf(wc[c + 3], W1s[(c + 3) * 64 + d], a3);
    }
    M[oh * DM + d_base + d] = (a0 + a1) + (a2 + a3);

    if (blockIdx.x == 0) {
        // s[oh]: wave oh reduces dot(wc, b1) (+bc for lo half)
        float p = wc[d] * b1[d];
        if (d < LEN - 64) p = fmaf(wc[d + 64], b1[d + 64], p);
#pragma unroll
        for (int m = 32; m >= 1; m >>= 1) p += __shfl_xor(p, m, 64);
        if (d == 0) s[oh] = p + ((half == 0) ? bc[o] : 0.f);
    }
}

__global__ __launch_bounds__(256) void edge_main(
    const float* __restrict__ x, const float* __restrict__ M,
    const float* __restrict__ s, float* __restrict__ out) {
    const int b = blockIdx.x;
    const int lane = threadIdx.x & 63;
    const int wave = threadIdx.x >> 6;

    const float* xb = x + (size_t)b * (NA * DM);

    // Issue ALL of this wave's x loads first (wave 0: rows {0,4,8,12};
    // waves 1-3: {w, w+4, w+8}) — 6-8 x 16B loads in flight per wave
    // before any dependent compute. `a < NA` is wave-uniform.
    fv4 xA[4], xB[4];
#pragma unroll
    for (int k = 0; k < 4; ++k) {
        const int a = wave + 4 * k;
        if (a < NA) {
            xA[k] = *(const fv4*)(xb + a * DM + lane * 4);
            xB[k] = *(const fv4*)(xb + a * DM + 256 + lane * 4);
        }
    }

    // Per-lane M slices: lane covers d = lane*4..+3 and d = 256+lane*4..+3
    fv4 mA[NOH], mB[NOH];
#pragma unroll
    for (int oh = 0; oh < NOH; ++oh) {
        mA[oh] = *(const fv4*)(M + oh * DM + lane * 4);
        mB[oh] = *(const fv4*)(M + oh * DM + 256 + lane * 4);
    }
    const float s_lane = s[lane & 7];

    const bool m1 = (lane & 1) != 0;
    const bool m2 = (lane & 2) != 0;
    const bool m4 = (lane & 4) != 0;

    __shared__ float G[NA][NOH];

#pragma unroll
    for (int k = 0; k < 4; ++k) {
        const int a = wave + 4 * k;
        if (a < NA) {
            float acc[NOH];
#pragma unroll
            for (int oh = 0; oh < NOH; ++oh) {
                float v = xA[k].x * mA[oh].x;
                v = fmaf(xA[k].y, mA[oh].y, v);
                v = fmaf(xA[k].z, mA[oh].z, v);
                v = fmaf(xA[k].w, mA[oh].w, v);
                v = fmaf(xB[k].x, mB[oh].x, v);
                v = fmaf(xB[k].y, mB[oh].y, v);
                v = fmaf(xB[k].z, mB[oh].z, v);
                v = fmaf(xB[k].w, mB[oh].w, v);
                acc[oh] = v;
            }
            // transpose-reduce: 3 merge steps leave lane l holding oh=(l&7)'s
            // 8-lane partial; 3 butterflies finish the 64 lanes.
            float r1[4];
#pragma unroll
            for (int q = 0; q < 4; ++q) {
                float keep = m1 ? acc[2 * q + 1] : acc[2 * q];
                float send = m1 ? acc[2 * q]     : acc[2 * q + 1];
                r1[q] = keep + __shfl_xor(send, 1, 64);
            }
            float r2[2];
#pragma unroll
            for (int q = 0; q < 2; ++q) {
                float keep = m2 ? r1[2 * q + 1] : r1[2 * q];
                float send = m2 ? r1[2 * q]     : r1[2 * q + 1];
                r2[q] = keep + __shfl_xor(send, 2, 64);
            }
            float keep = m4 ? r2[1] : r2[0];
            float send = m4 ? r2[0] : r2[1];
            float t = keep + __shfl_xor(send, 4, 64);
            t += __shfl_xor(t, 8, 64);
            t += __shfl_xor(t, 16, 64);
            t += __shfl_xor(t, 32, 64);
            if (lane < NOH) G[a][lane] = t + s_lane;
        }
    }
    __syncthreads();

    // 13*13 pairs, one float4 (4 outputs) per thread, coalesced
    const int t = threadIdx.x;
    if (t < NA * NA) {
        int i = t / NA, j = t % NA;
        int lo = i < j ? i : j;
        int hi = i < j ? j : i;
        fv4 v;
        v.x = G[lo][0] + G[hi][4];
        v.y = G[lo][1] + G[hi][5];
        v.z = G[lo][2] + G[hi][6];
        v.w = G[lo][3] + G[hi][7];
        ((fv4*)(out + (size_t)b * (NA * NA * 4)))[t] = v;
    }
}

extern "C" void kernel_launch(void* const* d_in, const int* in_sizes, int n_in,
                              void* d_out, int out_size, void* d_ws, size_t ws_size,
                              hipStream_t stream) {
    const float* x  = (const float*)d_in[0];
    const float* W1 = (const float*)d_in[1];
    const float* b1 = (const float*)d_in[2];
    const float* Wc = (const float*)d_in[3];
    const float* bc = (const float*)d_in[4];
    float* out = (float*)d_out;
    const int B = in_sizes[0] / (NA * DM);   // 8192

    float* M = (float*)d_ws;            // 8*512 floats = 16 KB
    float* s = M + NOH * DM;            // 8 floats

    precompute_M<<<8, 512, 0, stream>>>(W1, b1, Wc, bc, M, s);
    edge_main<<<B, 256, 0, stream>>>(x, M, s, out);
}